// Round 2
// baseline (808.842 us; speedup 1.0000x reference)
//
#include <hip/hip_runtime.h>
#include <hip/hip_bf16.h>
#include <math.h>

#define BB 128
#define SS 256
#define HH 512
#define VV 50000
#define VEXT 50012
#define NBLK 782
#define PST 784

typedef __bf16 bf16x8 __attribute__((ext_vector_type(8)));
typedef float f32x4 __attribute__((ext_vector_type(4)));

__device__ __forceinline__ float fast_tanh(float x) {
  float e = __expf(2.0f * x);
  return 1.0f - 2.0f / (e + 1.0f);
}
__device__ __forceinline__ float fast_sigmoid(float x) {
  return 1.0f / (1.0f + __expf(-x));
}
__device__ __forceinline__ bf16x8 cvt8(const float* p) {
  float4 a = *(const float4*)p;
  float4 b = *(const float4*)(p + 4);
  bf16x8 r;
  r[0] = (__bf16)a.x; r[1] = (__bf16)a.y; r[2] = (__bf16)a.z; r[3] = (__bf16)a.w;
  r[4] = (__bf16)b.x; r[5] = (__bf16)b.y; r[6] = (__bf16)b.z; r[7] = (__bf16)b.w;
  return r;
}

// ---- combined pack: Wc (K=512), attn_W cols 512..1024 (K=512), encoded -> fragment order
// fragment (tile,ks,lane=(q*16+m)) = src[(tile*16+m)*ldw + coff + ks*32 + q*8 .. +8]
__global__ void k_pack_all(const float* __restrict__ Wc_w, const float* __restrict__ attn_W,
                           const float* __restrict__ enc,
                           __hip_bfloat16* __restrict__ wc_bf,
                           __hip_bfloat16* __restrict__ wa_bf,
                           __hip_bfloat16* __restrict__ epk,
                           float* __restrict__ pc_total) {
  int i = blockIdx.x * 256 + threadIdx.x;
  if (blockIdx.x == 0 && threadIdx.x == 0) pc_total[0] = 0.f;
  if (i < 65536) {  // Wc_w: 1024 rows x 512
    int l = i & 63, ks = (i >> 6) & 15, tile = i >> 10;
    int m = l & 15, q = l >> 4;
    const float* p = Wc_w + (size_t)(tile * 16 + m) * 512 + ks * 32 + q * 8;
    *(bf16x8*)(wc_bf + (size_t)i * 8) = cvt8(p);
  } else if (i < 98304) {  // attn_W: 512 rows, cols 512..1024
    int j = i - 65536;
    int l = j & 63, ks = (j >> 6) & 15, tile = j >> 10;
    int m = l & 15, q = l >> 4;
    const float* p = attn_W + (size_t)(tile * 16 + m) * 1024 + 512 + ks * 32 + q * 8;
    *(bf16x8*)(wa_bf + (size_t)j * 8) = cvt8(p);
  } else if (i < 98304 + 2097152) {  // encoded: [b][st][ks][lane][8]
    int j = i - 98304;
    int l = j & 63, ks = (j >> 6) & 15, st = (j >> 10) & 15, b = j >> 14;
    int m = l & 15, q = l >> 4;
    const float* p = enc + ((size_t)b * SS + st * 16 + m) * HH + ks * 32 + q * 8;
    *(bf16x8*)(epk + (size_t)j * 8) = cvt8(p);
  }
}

// ---- generic MFMA GEMM: C(128 x N) = A(128x512) @ B(N rows).T + bias (template version)
template <int LDB, bool GATHER>
__global__ __launch_bounds__(256, 2) void k_gemm_bt(
    const float* __restrict__ A, const float* __restrict__ B,
    const float* __restrict__ bias, float* __restrict__ C, int ldc,
    const int* __restrict__ gidx) {
  __shared__ __hip_bfloat16 ylds[128 * 72];
  const int t = threadIdx.x;
  const int l = t & 63, w = t >> 6;
  const int m = l & 15, q = l >> 4;
  const int n = blockIdx.x * 64 + w * 16 + m;
  const float* wrow = B + (size_t)n * LDB;
  f32x4 acc[8];
#pragma unroll
  for (int mt = 0; mt < 8; ++mt) acc[mt] = (f32x4){0.f, 0.f, 0.f, 0.f};

  for (int kt = 0; kt < 512; kt += 64) {
    __syncthreads();
#pragma unroll
    for (int i = 0; i < 8; ++i) {
      int f = t + i * 256;
      int row = f >> 4, c4 = f & 15;
      const float* arow;
      if (GATHER)
        arow = A + (size_t)gidx[row] * 512;
      else
        arow = A + (size_t)row * 512;
      float4 v = *(const float4*)(arow + kt + c4 * 4);
      __hip_bfloat16* d = ylds + row * 72 + c4 * 4;
      d[0] = __float2bfloat16(v.x); d[1] = __float2bfloat16(v.y);
      d[2] = __float2bfloat16(v.z); d[3] = __float2bfloat16(v.w);
    }
    __syncthreads();
#pragma unroll
    for (int ksl = 0; ksl < 2; ++ksl) {
      bf16x8 bfr = cvt8(wrow + kt + ksl * 32 + q * 8);
#pragma unroll
      for (int mt = 0; mt < 8; ++mt) {
        bf16x8 af = *(const bf16x8*)(ylds + (mt * 16 + m) * 72 + ksl * 32 + q * 8);
        acc[mt] = __builtin_amdgcn_mfma_f32_16x16x32_bf16(af, bfr, acc[mt], 0, 0, 0);
      }
    }
  }
  float bv = bias[n];
#pragma unroll
  for (int mt = 0; mt < 8; ++mt) {
#pragma unroll
    for (int r = 0; r < 4; ++r) {
      int rowm = mt * 16 + q * 4 + r;
      C[(size_t)rowm * ldc + n] = acc[mt][r] + bv;
    }
  }
}

// ---- dual GEMM: blocks [0,nb0) do GEMM0, rest do GEMM1 (runtime ldb/ldc/gather) ----
__global__ __launch_bounds__(256, 2) void k_gemm_dual(
    const float* __restrict__ A0, const float* __restrict__ B0,
    const float* __restrict__ b0, float* __restrict__ C0, int ldb0, int ldc0, int nb0,
    const float* __restrict__ A1, const float* __restrict__ B1,
    const float* __restrict__ b1, float* __restrict__ C1, int ldb1, int ldc1,
    const int* __restrict__ gidx1) {
  __shared__ __hip_bfloat16 ylds[128 * 72];
  const float* A; const float* Bw; const float* bias; float* C;
  int ldb, ldc, blk; const int* gidx;
  if ((int)blockIdx.x < nb0) {
    A = A0; Bw = B0; bias = b0; C = C0; ldb = ldb0; ldc = ldc0; gidx = nullptr; blk = blockIdx.x;
  } else {
    A = A1; Bw = B1; bias = b1; C = C1; ldb = ldb1; ldc = ldc1; gidx = gidx1; blk = blockIdx.x - nb0;
  }
  const int t = threadIdx.x;
  const int l = t & 63, w = t >> 6;
  const int m = l & 15, q = l >> 4;
  const int n = blk * 64 + w * 16 + m;
  const float* wrow = Bw + (size_t)n * ldb;
  f32x4 acc[8];
#pragma unroll
  for (int mt = 0; mt < 8; ++mt) acc[mt] = (f32x4){0.f, 0.f, 0.f, 0.f};

  for (int kt = 0; kt < 512; kt += 64) {
    __syncthreads();
#pragma unroll
    for (int i = 0; i < 8; ++i) {
      int f = t + i * 256;
      int row = f >> 4, c4 = f & 15;
      const float* arow = gidx ? (A + (size_t)gidx[row] * 512) : (A + (size_t)row * 512);
      float4 v = *(const float4*)(arow + kt + c4 * 4);
      __hip_bfloat16* d = ylds + row * 72 + c4 * 4;
      d[0] = __float2bfloat16(v.x); d[1] = __float2bfloat16(v.y);
      d[2] = __float2bfloat16(v.z); d[3] = __float2bfloat16(v.w);
    }
    __syncthreads();
#pragma unroll
    for (int ksl = 0; ksl < 2; ++ksl) {
      bf16x8 bfr = cvt8(wrow + kt + ksl * 32 + q * 8);
#pragma unroll
      for (int mt = 0; mt < 8; ++mt) {
        bf16x8 af = *(const bf16x8*)(ylds + (mt * 16 + m) * 72 + ksl * 32 + q * 8);
        acc[mt] = __builtin_amdgcn_mfma_f32_16x16x32_bf16(af, bfr, acc[mt], 0, 0, 0);
      }
    }
  }
  float bv = bias[n];
#pragma unroll
  for (int mt = 0; mt < 8; ++mt) {
#pragma unroll
    for (int r = 0; r < 4; ++r) {
      int rowm = mt * 16 + q * 4 + r;
      C[(size_t)rowm * ldc + n] = acc[mt][r] + bv;
    }
  }
}

// ---- GRU gates elementwise ----
__global__ void k_gates(const float* __restrict__ gi, const float* __restrict__ gh,
                        const float* __restrict__ prevv, float* __restrict__ state,
                        float* __restrict__ state_out) {
  int i = blockIdx.x * 256 + threadIdx.x;  // 65536
  int b = i >> 9, h = i & 511;
  const float* gib = gi + (size_t)b * 1536;
  const float* ghb = gh + (size_t)b * 1536;
  float ir = gib[h], iz = gib[512 + h], inn = gib[1024 + h];
  float hr = ghb[h], hz = ghb[512 + h], hn = ghb[1024 + h];
  float r = fast_sigmoid(ir + hr);
  float z = fast_sigmoid(iz + hz);
  float n = fast_tanh(inn + r * hn);
  float st = (1.f - z) * n + z * prevv[i];
  state[i] = st;
  state_out[i] = st;
}

// ---- fused MFMA v2: out[b,s] = sum_n tanh(enc[b,s,:].W[n,:] + bias[n]) * mult[n]
// grid (B, 4); each wave owns one 16-row s-tile, loops over all n.
// W tile (32 n-rows) cooperatively staged in LDS once per block -> W traffic /4.
template <int NTOT, int MODE>
__global__ __launch_bounds__(256, 2) void k_fused2(
    const __hip_bfloat16* __restrict__ epack, const __hip_bfloat16* __restrict__ wpk,
    const float* __restrict__ biasA, const float* __restrict__ multA,
    const int* __restrict__ enc_idx, float* __restrict__ out) {
  const int b = blockIdx.x, t = threadIdx.x;
  const int l = t & 63, w = t >> 6;
  const int m = l & 15, q = l >> 4;
  const int st = blockIdx.y * 4 + w;
  __shared__ __hip_bfloat16 wstage[32 * 512];  // 32KB: 2 n-tiles x 16 ks x 64 lanes x 8
  __shared__ float bias_l[NTOT];
  __shared__ float mult_l[NTOT];
  const float* bias_base = (MODE == 0) ? biasA + (size_t)b * HH : biasA;
  const float* mult_base = (MODE == 0) ? multA : multA + (size_t)b * 1024;
  for (int i = t; i < NTOT; i += 256) {
    bias_l[i] = bias_base[i];
    mult_l[i] = mult_base[i];
  }
  const __hip_bfloat16* ep = epack + ((size_t)(b * 16 + st) * 16) * 512 + (size_t)l * 8;
  bf16x8 afr[16];
#pragma unroll
  for (int ks = 0; ks < 16; ++ks) afr[ks] = *(const bf16x8*)(ep + ks * 512);

  float part[4] = {0.f, 0.f, 0.f, 0.f};
  for (int nb = 0; nb < NTOT; nb += 32) {
    __syncthreads();  // protect prior-iter LDS reads (and bias_l on first iter)
    const bf16x8* src = (const bf16x8*)(wpk + (size_t)nb * 512);
    bf16x8* dstv = (bf16x8*)wstage;
#pragma unroll
    for (int i = 0; i < 8; ++i) dstv[t + i * 256] = src[t + i * 256];
    __syncthreads();
#pragma unroll
    for (int nt = 0; nt < 2; ++nt) {
      const __hip_bfloat16* wbase = wstage + nt * 8192 + (size_t)l * 8;
      f32x4 a0 = {0.f, 0.f, 0.f, 0.f}, a1 = a0, a2 = a0, a3 = a0;
#pragma unroll
      for (int j = 0; j < 4; ++j) {
        a0 = __builtin_amdgcn_mfma_f32_16x16x32_bf16(afr[j], *(const bf16x8*)(wbase + j * 512), a0, 0, 0, 0);
        a1 = __builtin_amdgcn_mfma_f32_16x16x32_bf16(afr[4 + j], *(const bf16x8*)(wbase + (4 + j) * 512), a1, 0, 0, 0);
        a2 = __builtin_amdgcn_mfma_f32_16x16x32_bf16(afr[8 + j], *(const bf16x8*)(wbase + (8 + j) * 512), a2, 0, 0, 0);
        a3 = __builtin_amdgcn_mfma_f32_16x16x32_bf16(afr[12 + j], *(const bf16x8*)(wbase + (12 + j) * 512), a3, 0, 0, 0);
      }
      f32x4 acc = (a0 + a1) + (a2 + a3);
      const int n = nb + nt * 16 + m;
      float bias = bias_l[n];
      float mul = mult_l[n];
#pragma unroll
      for (int r = 0; r < 4; ++r) part[r] += fast_tanh(acc[r] + bias) * mul;
    }
  }
#pragma unroll
  for (int r = 0; r < 4; ++r) {
    part[r] += __shfl_xor(part[r], 1, 64);
    part[r] += __shfl_xor(part[r], 2, 64);
    part[r] += __shfl_xor(part[r], 4, 64);
    part[r] += __shfl_xor(part[r], 8, 64);
  }
  if (m == 0) {
#pragma unroll
    for (int r = 0; r < 4; ++r) {
      int s = st * 16 + q * 4 + r;
      float v = part[r];
      if (MODE == 1 && enc_idx[b * SS + s] == 0) v -= 1000.0f;
      out[b * SS + s] = v;
    }
  }
}

// ---- score_g via MFMA, barrier-free, fused per-block row max/expsum partials ----
__global__ __launch_bounds__(256, 4) void k_score_g2(
    const __hip_bfloat16* __restrict__ ypk, const float* __restrict__ Wo_w,
    const float* __restrict__ Wo_b, float* __restrict__ sg,
    float* __restrict__ ppmax, float* __restrict__ ppsum) {
  const int t = threadIdx.x;
  const int l = t & 63, w = t >> 6;
  const int m = l & 15, q = l >> 4;
  const int blk = blockIdx.x;
  const int n = blk * 64 + w * 16 + m;
  const int n_ld = (n < VV) ? n : (VV - 1);
  const float* wrow = Wo_w + (size_t)n_ld * 1024;
  f32x4 acc[8];
#pragma unroll
  for (int mt = 0; mt < 8; ++mt) acc[mt] = (f32x4){0.f, 0.f, 0.f, 0.f};

  for (int ks = 0; ks < 32; ++ks) {
    bf16x8 bfr = cvt8(wrow + ks * 32 + q * 8);
#pragma unroll
    for (int mt = 0; mt < 8; ++mt) {
      bf16x8 af = *(const bf16x8*)(ypk + (((size_t)mt * 32 + ks) * 64 + l) * 8);
      acc[mt] = __builtin_amdgcn_mfma_f32_16x16x32_bf16(af, bfr, acc[mt], 0, 0, 0);
    }
  }

  float bv = (n < VV) ? Wo_b[n] : 0.f;
#pragma unroll
  for (int mt = 0; mt < 8; ++mt) {
#pragma unroll
    for (int r = 0; r < 4; ++r) {
      float v = acc[mt][r] + bv;
      if (n < VV)
        sg[(size_t)(mt * 16 + q * 4 + r) * VV + n] = v;
      else
        v = -1e30f;
      acc[mt][r] = v;
    }
  }

  __shared__ float redA[4][128];
  __shared__ float MS[128];
#pragma unroll
  for (int mt = 0; mt < 8; ++mt) {
#pragma unroll
    for (int r = 0; r < 4; ++r) {
      float mx = acc[mt][r];
      mx = fmaxf(mx, __shfl_xor(mx, 1, 64));
      mx = fmaxf(mx, __shfl_xor(mx, 2, 64));
      mx = fmaxf(mx, __shfl_xor(mx, 4, 64));
      mx = fmaxf(mx, __shfl_xor(mx, 8, 64));
      if (m == 0) redA[w][mt * 16 + q * 4 + r] = mx;
    }
  }
  __syncthreads();
  if (t < 128)
    MS[t] = fmaxf(fmaxf(redA[0][t], redA[1][t]), fmaxf(redA[2][t], redA[3][t]));
  __syncthreads();
#pragma unroll
  for (int mt = 0; mt < 8; ++mt) {
#pragma unroll
    for (int r = 0; r < 4; ++r) {
      float s = __expf(acc[mt][r] - MS[mt * 16 + q * 4 + r]);
      s += __shfl_xor(s, 1, 64);
      s += __shfl_xor(s, 2, 64);
      s += __shfl_xor(s, 4, 64);
      s += __shfl_xor(s, 8, 64);
      if (m == 0) redA[w][mt * 16 + q * 4 + r] = s;
    }
  }
  __syncthreads();
  if (t < 128) {
    ppmax[(size_t)t * PST + blk] = MS[t];
    ppsum[(size_t)t * PST + blk] = redA[0][t] + redA[1][t] + redA[2][t] + redA[3][t];
  }
}

// ---- merge partials + sc, and compute prob_c / pc_total (fused old probc math) ----
__global__ void k_merge(const float* __restrict__ ppmax, const float* __restrict__ ppsum,
                        const float* __restrict__ sc,
                        float* __restrict__ rmax, float* __restrict__ rsum,
                        float* __restrict__ prob_c, float* __restrict__ pc_total) {
  const int row = blockIdx.x, t = threadIdx.x;  // 256 threads
  __shared__ float rb[8];
  __shared__ float MS[2];
  float x_sc = sc[row * SS + t];
  float mrow = x_sc;
  for (int i = t; i < NBLK; i += 256) mrow = fmaxf(mrow, ppmax[(size_t)row * PST + i]);
  for (int off = 32; off > 0; off >>= 1) mrow = fmaxf(mrow, __shfl_xor(mrow, off, 64));
  if ((t & 63) == 0) rb[t >> 6] = mrow;
  __syncthreads();
  if (t == 0) MS[0] = fmaxf(fmaxf(rb[0], rb[1]), fmaxf(rb[2], rb[3]));
  __syncthreads();
  float M = MS[0];
  float e_sc = __expf(x_sc - M);
  float s = e_sc;
  for (int i = t; i < NBLK; i += 256)
    s += ppsum[(size_t)row * PST + i] * __expf(ppmax[(size_t)row * PST + i] - M);
  for (int off = 32; off > 0; off >>= 1) s += __shfl_xor(s, off, 64);
  if ((t & 63) == 0) rb[4 + (t >> 6)] = s;
  __syncthreads();
  if (t == 0) MS[1] = rb[4] + rb[5] + rb[6] + rb[7];
  __syncthreads();
  float S = MS[1];
  if (t == 0) {
    rmax[row] = M;
    rsum[row] = S;
  }
  float pc = e_sc / S;
  prob_c[row * SS + t] = pc;
  float ps = pc;
  for (int off = 32; off > 0; off >>= 1) ps += __shfl_xor(ps, off, 64);
  if ((t & 63) == 0) rb[t >> 6] = ps;
  __syncthreads();
  if (t == 0) atomicAdd(pc_total, rb[0] + rb[1] + rb[2] + rb[3]);
}

// ---- fused softmax + context + y assembly + ypk pack ----
__global__ void k_ctx(const float* __restrict__ score, const float* __restrict__ enc,
                      const float* __restrict__ state, float* __restrict__ y,
                      __hip_bfloat16* __restrict__ ypk) {
  const int b = blockIdx.x, hc = blockIdx.y, t = threadIdx.x;  // 128 threads
  __shared__ float aws[SS];
  __shared__ float rb[4];
  float x0 = score[b * SS + t], x1 = score[b * SS + t + 128];
  float mx = fmaxf(x0, x1);
  for (int off = 32; off > 0; off >>= 1) mx = fmaxf(mx, __shfl_xor(mx, off, 64));
  if ((t & 63) == 0) rb[t >> 6] = mx;
  __syncthreads();
  mx = fmaxf(rb[0], rb[1]);
  float e0 = __expf(x0 - mx), e1 = __expf(x1 - mx);
  float s = e0 + e1;
  for (int off = 32; off > 0; off >>= 1) s += __shfl_xor(s, off, 64);
  if ((t & 63) == 0) rb[2 + (t >> 6)] = s;
  __syncthreads();
  float inv = 1.0f / (rb[2] + rb[3]);
  aws[t] = e0 * inv;
  aws[t + 128] = e1 * inv;
  __syncthreads();
  const int h = hc * 128 + t;
  float acc = 0.f;
#pragma unroll 8
  for (int ss = 0; ss < SS; ++ss) acc += aws[ss] * enc[((size_t)b * SS + ss) * HH + h];
  float sv = state[b * HH + h];
  y[(size_t)b * 1024 + h] = sv;
  y[(size_t)b * 1024 + HH + h] = acc;
  // ypk pack: element (row=b, col): idx = ((tile*32 + ks)*64 + q*16 + m)*8 + e
  const int tile = b >> 4, mm = b & 15;
  const int c0 = h, c1 = HH + h;
  ypk[(((size_t)tile * 32 + (c0 >> 5)) * 64 + ((c0 & 31) >> 3) * 16 + mm) * 8 + (c0 & 7)] =
      __float2bfloat16(sv);
  ypk[(((size_t)tile * 32 + (c1 >> 5)) * 64 + ((c1 & 31) >> 3) * 16 + mm) * 8 + (c1 & 7)] =
      __float2bfloat16(acc);
}

__global__ void k_write_probg(const float* __restrict__ sg,
                              const float* __restrict__ rmax,
                              const float* __restrict__ rsum,
                              float* __restrict__ out) {
  int i = blockIdx.x * 256 + threadIdx.x;
  const int total = BB * VEXT;
  if (i >= total) return;
  int b = i / VEXT;
  int v = i - b * VEXT;
  float val;
  if (v < VV)
    val = __expf(sg[(size_t)b * VV + v] - rmax[b]) / rsum[b];
  else
    val = 1e-4f;
  out[i] = val;
}

// ---- weighted_new (h-split) + prob_c scatter into out (hc==0 only; runs after probg) ----
__global__ void k_weighted2(const int* __restrict__ enc_idx,
                            const int* __restrict__ input_idx,
                            const float* __restrict__ prob_c,
                            const float* __restrict__ pc_total,
                            const float* __restrict__ enc,
                            float* __restrict__ wout,
                            float* __restrict__ out) {
  const int b = blockIdx.x, hc = blockIdx.y, t = threadIdx.x;  // 128 threads
  __shared__ float f[SS];
  __shared__ float rb[2];
  const int idx_in = input_idx[b];
  const int e0i = enc_idx[b * SS + t], e1i = enc_idx[b * SS + t + 128];
  const float p0 = prob_c[b * SS + t], p1 = prob_c[b * SS + t + 128];
  if (hc == 0) {
    atomicAdd(&out[(size_t)b * VEXT + e0i], p0);
    atomicAdd(&out[(size_t)b * VEXT + e1i], p1);
  }
  int m0 = (e0i == idx_in) ? 1 : 0;
  int m1 = (e1i == idx_in) ? 1 : 0;
  float lsum = (float)(m0 + m1);
  for (int off = 32; off > 0; off >>= 1) lsum += __shfl_xor(lsum, off, 64);
  if ((t & 63) == 0) rb[t >> 6] = lsum;
  __syncthreads();
  float tot = rb[0] + rb[1];
  float norm = (tot > 1.0f) ? 1.0f / tot : 1.0f;
  float inv_pct = 1.0f / pc_total[0];
  f[t] = m0 ? p0 * inv_pct * norm : 0.f;
  f[t + 128] = m1 ? p1 * inv_pct * norm : 0.f;
  __syncthreads();
  const int h = hc * 128 + t;
  float acc = 0.f;
  for (int ss = 0; ss < SS; ++ss) acc += f[ss] * enc[((size_t)b * SS + ss) * HH + h];
  wout[b * HH + h] = acc;
}

extern "C" void kernel_launch(void* const* d_in, const int* in_sizes, int n_in,
                              void* d_out, int out_size, void* d_ws, size_t ws_size,
                              hipStream_t stream) {
  const int* input_idx = (const int*)d_in[0];
  const float* encoded = (const float*)d_in[1];
  const int* encoded_idx = (const int*)d_in[2];
  const float* prev_state = (const float*)d_in[3];
  const float* embed = (const float*)d_in[5];
  const float* Ws_w = (const float*)d_in[6];
  const float* Ws_b = (const float*)d_in[7];
  const float* gWih = (const float*)d_in[8];
  const float* gWhh = (const float*)d_in[9];
  const float* gbih = (const float*)d_in[10];
  const float* gbhh = (const float*)d_in[11];
  const float* attn_W = (const float*)d_in[12];
  const float* attn_b = (const float*)d_in[13];
  const float* attn_v = (const float*)d_in[14];
  const float* Wo_w = (const float*)d_in[15];
  const float* Wo_b = (const float*)d_in[16];
  const float* Wc_w = (const float*)d_in[17];
  const float* Wc_b = (const float*)d_in[18];

  float* out = (float*)d_out;
  float* out_state = out + (size_t)BB * VEXT;
  float* out_weighted = out_state + BB * HH;

  float* ws = (float*)d_ws;
  float* prevv = ws;                          // 65536
  float* state = prevv + BB * HH;             // 65536
  float* hW = state + BB * HH;                // 65536
  float* ascore = hW + BB * HH;               // 32768
  float* aw = ascore + BB * SS;               // 32768 (unused, kept for layout)
  float* y = aw + BB * SS;                    // 131072
  float* sg = y + BB * 1024;                  // 6400000 (gi/gh alias its head pre-score_g)
  float* sc = sg + (size_t)BB * VV;           // 32768
  float* prob_c = sc + BB * SS;               // 32768
  float* rmax = prob_c + BB * SS;             // 128
  float* rsum = rmax + BB;                    // 128
  float* pc_total = rsum + BB;                // 64 (padded)
  float* ppmax = pc_total + 64;               // 128*784
  float* ppsum = ppmax + (size_t)BB * PST;    // 128*784
  __hip_bfloat16* wc_bf = (__hip_bfloat16*)(ppsum + (size_t)BB * PST);  // 1024*512
  __hip_bfloat16* wa_bf = wc_bf + (size_t)1024 * HH;                    // 512*512
  __hip_bfloat16* epack = wa_bf + (size_t)512 * HH;                     // 128*256*512
  __hip_bfloat16* ypk = epack + (size_t)BB * SS * HH;                   // 128*1024

  float* gi = sg;                 // 128*1536, dead before sg is written
  float* gh = sg + BB * 1536;     // 128*1536

  // pack weights + encoded into MFMA fragment order; zero pc_total
  k_pack_all<<<8576, 256, 0, stream>>>(Wc_w, attn_W, encoded, wc_bf, wa_bf, epack, pc_total);

  // GRU chain: prevv + gi in one dual launch (independent), then gh, gates, hW
  k_gemm_dual<<<32, 256, 0, stream>>>(prev_state, Ws_w, Ws_b, prevv, 512, 512, 8,
                                      embed, gWih, gbih, gi, 1024, 1536, input_idx);
  k_gemm_bt<512, false><<<24, 256, 0, stream>>>(prevv, gWhh, gbhh, gh, 1536, nullptr);
  k_gates<<<256, 256, 0, stream>>>(gi, gh, prevv, state, out_state);
  k_gemm_bt<1024, false><<<8, 256, 0, stream>>>(state, attn_W, attn_b, hW, 512, nullptr);

  k_fused2<HH, 0><<<dim3(BB, 4), 256, 0, stream>>>(epack, wa_bf, hW, attn_v,
                                                   nullptr, ascore);
  k_ctx<<<dim3(BB, 4), 128, 0, stream>>>(ascore, encoded, state, y, ypk);

  k_score_g2<<<NBLK, 256, 0, stream>>>(ypk, Wo_w, Wo_b, sg, ppmax, ppsum);
  k_fused2<1024, 1><<<dim3(BB, 4), 256, 0, stream>>>(epack, wc_bf, Wc_b, y,
                                                     encoded_idx, sc);

  k_merge<<<BB, 256, 0, stream>>>(ppmax, ppsum, sc, rmax, rsum, prob_c, pc_total);
  k_write_probg<<<(BB * VEXT + 255) / 256, 256, 0, stream>>>(sg, rmax, rsum, out);
  k_weighted2<<<dim3(BB, 4), 128, 0, stream>>>(encoded_idx, input_idx, prob_c, pc_total,
                                               encoded, out_weighted, out);
}

// Round 3
// 697.257 us; speedup vs baseline: 1.1600x; 1.1600x over previous
//
#include <hip/hip_runtime.h>
#include <hip/hip_bf16.h>
#include <math.h>

#define BB 128
#define SS 256
#define HH 512
#define VV 50000
#define VEXT 50012
#define NBLK 782
#define PST 784

typedef __bf16 bf16x8 __attribute__((ext_vector_type(8)));
typedef float f32x4 __attribute__((ext_vector_type(4)));

__device__ __forceinline__ float fast_tanh(float x) {
  float e = __expf(2.0f * x);
  return 1.0f - 2.0f / (e + 1.0f);
}
__device__ __forceinline__ float fast_sigmoid(float x) {
  return 1.0f / (1.0f + __expf(-x));
}
__device__ __forceinline__ bf16x8 cvt8(const float* p) {
  float4 a = *(const float4*)p;
  float4 b = *(const float4*)(p + 4);
  bf16x8 r;
  r[0] = (__bf16)a.x; r[1] = (__bf16)a.y; r[2] = (__bf16)a.z; r[3] = (__bf16)a.w;
  r[4] = (__bf16)b.x; r[5] = (__bf16)b.y; r[6] = (__bf16)b.z; r[7] = (__bf16)b.w;
  return r;
}

// async 16B global -> LDS (wave-uniform LDS base + lane*16; per-lane global addr)
__device__ __forceinline__ void gload_lds16(const bf16x8* g, bf16x8* l) {
  __builtin_amdgcn_global_load_lds((const __attribute__((address_space(1))) void*)g,
                                   (__attribute__((address_space(3))) void*)l, 16, 0, 0);
}

// ---- combined pack: Wc (K=512), attn_W cols 512..1024 (K=512), encoded -> fragment order
// fragment (tile,ks,lane=(q*16+m)) = src[(tile*16+m)*ldw + coff + ks*32 + q*8 .. +8]
__global__ void k_pack_all(const float* __restrict__ Wc_w, const float* __restrict__ attn_W,
                           const float* __restrict__ enc,
                           __hip_bfloat16* __restrict__ wc_bf,
                           __hip_bfloat16* __restrict__ wa_bf,
                           __hip_bfloat16* __restrict__ epk,
                           float* __restrict__ pc_total) {
  int i = blockIdx.x * 256 + threadIdx.x;
  if (blockIdx.x == 0 && threadIdx.x == 0) pc_total[0] = 0.f;
  if (i < 65536) {  // Wc_w: 1024 rows x 512
    int l = i & 63, ks = (i >> 6) & 15, tile = i >> 10;
    int m = l & 15, q = l >> 4;
    const float* p = Wc_w + (size_t)(tile * 16 + m) * 512 + ks * 32 + q * 8;
    *(bf16x8*)(wc_bf + (size_t)i * 8) = cvt8(p);
  } else if (i < 98304) {  // attn_W: 512 rows, cols 512..1024
    int j = i - 65536;
    int l = j & 63, ks = (j >> 6) & 15, tile = j >> 10;
    int m = l & 15, q = l >> 4;
    const float* p = attn_W + (size_t)(tile * 16 + m) * 1024 + 512 + ks * 32 + q * 8;
    *(bf16x8*)(wa_bf + (size_t)j * 8) = cvt8(p);
  } else if (i < 98304 + 2097152) {  // encoded: [b][st][ks][lane][8]
    int j = i - 98304;
    int l = j & 63, ks = (j >> 6) & 15, st = (j >> 10) & 15, b = j >> 14;
    int m = l & 15, q = l >> 4;
    const float* p = enc + ((size_t)b * SS + st * 16 + m) * HH + ks * 32 + q * 8;
    *(bf16x8*)(epk + (size_t)j * 8) = cvt8(p);
  }
}

// ---- generic MFMA GEMM: C(128 x N) = A(128x512) @ B(N rows).T + bias (template version)
template <int LDB, bool GATHER>
__global__ __launch_bounds__(256, 2) void k_gemm_bt(
    const float* __restrict__ A, const float* __restrict__ B,
    const float* __restrict__ bias, float* __restrict__ C, int ldc,
    const int* __restrict__ gidx) {
  __shared__ __hip_bfloat16 ylds[128 * 72];
  const int t = threadIdx.x;
  const int l = t & 63, w = t >> 6;
  const int m = l & 15, q = l >> 4;
  const int n = blockIdx.x * 64 + w * 16 + m;
  const float* wrow = B + (size_t)n * LDB;
  f32x4 acc[8];
#pragma unroll
  for (int mt = 0; mt < 8; ++mt) acc[mt] = (f32x4){0.f, 0.f, 0.f, 0.f};

  for (int kt = 0; kt < 512; kt += 64) {
    __syncthreads();
#pragma unroll
    for (int i = 0; i < 8; ++i) {
      int f = t + i * 256;
      int row = f >> 4, c4 = f & 15;
      const float* arow;
      if (GATHER)
        arow = A + (size_t)gidx[row] * 512;
      else
        arow = A + (size_t)row * 512;
      float4 v = *(const float4*)(arow + kt + c4 * 4);
      __hip_bfloat16* d = ylds + row * 72 + c4 * 4;
      d[0] = __float2bfloat16(v.x); d[1] = __float2bfloat16(v.y);
      d[2] = __float2bfloat16(v.z); d[3] = __float2bfloat16(v.w);
    }
    __syncthreads();
#pragma unroll
    for (int ksl = 0; ksl < 2; ++ksl) {
      bf16x8 bfr = cvt8(wrow + kt + ksl * 32 + q * 8);
#pragma unroll
      for (int mt = 0; mt < 8; ++mt) {
        bf16x8 af = *(const bf16x8*)(ylds + (mt * 16 + m) * 72 + ksl * 32 + q * 8);
        acc[mt] = __builtin_amdgcn_mfma_f32_16x16x32_bf16(af, bfr, acc[mt], 0, 0, 0);
      }
    }
  }
  float bv = bias[n];
#pragma unroll
  for (int mt = 0; mt < 8; ++mt) {
#pragma unroll
    for (int r = 0; r < 4; ++r) {
      int rowm = mt * 16 + q * 4 + r;
      C[(size_t)rowm * ldc + n] = acc[mt][r] + bv;
    }
  }
}

// ---- dual GEMM: blocks [0,nb0) do GEMM0, rest do GEMM1 (runtime ldb/ldc/gather) ----
__global__ __launch_bounds__(256, 2) void k_gemm_dual(
    const float* __restrict__ A0, const float* __restrict__ B0,
    const float* __restrict__ b0, float* __restrict__ C0, int ldb0, int ldc0, int nb0,
    const float* __restrict__ A1, const float* __restrict__ B1,
    const float* __restrict__ b1, float* __restrict__ C1, int ldb1, int ldc1,
    const int* __restrict__ gidx1) {
  __shared__ __hip_bfloat16 ylds[128 * 72];
  const float* A; const float* Bw; const float* bias; float* C;
  int ldb, ldc, blk; const int* gidx;
  if ((int)blockIdx.x < nb0) {
    A = A0; Bw = B0; bias = b0; C = C0; ldb = ldb0; ldc = ldc0; gidx = nullptr; blk = blockIdx.x;
  } else {
    A = A1; Bw = B1; bias = b1; C = C1; ldb = ldb1; ldc = ldc1; gidx = gidx1; blk = blockIdx.x - nb0;
  }
  const int t = threadIdx.x;
  const int l = t & 63, w = t >> 6;
  const int m = l & 15, q = l >> 4;
  const int n = blk * 64 + w * 16 + m;
  const float* wrow = Bw + (size_t)n * ldb;
  f32x4 acc[8];
#pragma unroll
  for (int mt = 0; mt < 8; ++mt) acc[mt] = (f32x4){0.f, 0.f, 0.f, 0.f};

  for (int kt = 0; kt < 512; kt += 64) {
    __syncthreads();
#pragma unroll
    for (int i = 0; i < 8; ++i) {
      int f = t + i * 256;
      int row = f >> 4, c4 = f & 15;
      const float* arow = gidx ? (A + (size_t)gidx[row] * 512) : (A + (size_t)row * 512);
      float4 v = *(const float4*)(arow + kt + c4 * 4);
      __hip_bfloat16* d = ylds + row * 72 + c4 * 4;
      d[0] = __float2bfloat16(v.x); d[1] = __float2bfloat16(v.y);
      d[2] = __float2bfloat16(v.z); d[3] = __float2bfloat16(v.w);
    }
    __syncthreads();
#pragma unroll
    for (int ksl = 0; ksl < 2; ++ksl) {
      bf16x8 bfr = cvt8(wrow + kt + ksl * 32 + q * 8);
#pragma unroll
      for (int mt = 0; mt < 8; ++mt) {
        bf16x8 af = *(const bf16x8*)(ylds + (mt * 16 + m) * 72 + ksl * 32 + q * 8);
        acc[mt] = __builtin_amdgcn_mfma_f32_16x16x32_bf16(af, bfr, acc[mt], 0, 0, 0);
      }
    }
  }
  float bv = bias[n];
#pragma unroll
  for (int mt = 0; mt < 8; ++mt) {
#pragma unroll
    for (int r = 0; r < 4; ++r) {
      int rowm = mt * 16 + q * 4 + r;
      C[(size_t)rowm * ldc + n] = acc[mt][r] + bv;
    }
  }
}

// ---- GRU gates elementwise ----
__global__ void k_gates(const float* __restrict__ gi, const float* __restrict__ gh,
                        const float* __restrict__ prevv, float* __restrict__ state,
                        float* __restrict__ state_out) {
  int i = blockIdx.x * 256 + threadIdx.x;  // 65536
  int b = i >> 9, h = i & 511;
  const float* gib = gi + (size_t)b * 1536;
  const float* ghb = gh + (size_t)b * 1536;
  float ir = gib[h], iz = gib[512 + h], inn = gib[1024 + h];
  float hr = ghb[h], hz = ghb[512 + h], hn = ghb[1024 + h];
  float r = fast_sigmoid(ir + hr);
  float z = fast_sigmoid(iz + hz);
  float n = fast_tanh(inn + r * hn);
  float st = (1.f - z) * n + z * prevv[i];
  state[i] = st;
  state_out[i] = st;
}

// ---- fused MFMA v3: out[b,s] = sum_n tanh(enc[b,s,:].W[n,:] + bias[n]) * mult[n]
// grid (B, 4); wave owns one 16-row s-tile. W tile (32 n-rows, 32KB) double-buffered in
// LDS via async global_load_lds prefetch: stage tile t+1 while MFMAing tile t, one
// barrier per iteration (its vmcnt(0) drain lands AFTER compute -> latency hidden).
template <int NTOT, int MODE>
__global__ __launch_bounds__(256, 2) void k_fused3(
    const __hip_bfloat16* __restrict__ epack, const __hip_bfloat16* __restrict__ wpk,
    const float* __restrict__ biasA, const float* __restrict__ multA,
    const int* __restrict__ enc_idx, float* __restrict__ out) {
  const int b = blockIdx.x, t = threadIdx.x;
  const int l = t & 63, w = t >> 6;
  const int m = l & 15, q = l >> 4;
  const int st = blockIdx.y * 4 + w;
  __shared__ bf16x8 wbuf[2][2048];  // 2 x 32KB double buffer
  __shared__ float bias_l[NTOT];
  __shared__ float mult_l[NTOT];
  const float* bias_base = (MODE == 0) ? biasA + (size_t)b * HH : biasA;
  const float* mult_base = (MODE == 0) ? multA : multA + (size_t)b * 1024;
  for (int i = t; i < NTOT; i += 256) {
    bias_l[i] = bias_base[i];
    mult_l[i] = mult_base[i];
  }
  const __hip_bfloat16* ep = epack + ((size_t)(b * 16 + st) * 16) * 512 + (size_t)l * 8;
  bf16x8 afr[16];
#pragma unroll
  for (int ks = 0; ks < 16; ++ks) afr[ks] = *(const bf16x8*)(ep + ks * 512);

  const bf16x8* wv = (const bf16x8*)wpk;
  constexpr int NITER = NTOT / 32;
  // prologue: async-stage tile 0 into buf 0
#pragma unroll
  for (int i = 0; i < 8; ++i)
    gload_lds16(wv + w * 64 + i * 256 + l, &wbuf[0][w * 64 + i * 256]);
  __syncthreads();  // drains vmcnt(0) + barrier: buf0 ready, bias_l ready

  float part[4] = {0.f, 0.f, 0.f, 0.f};
  int cur = 0;
  for (int it = 0; it < NITER; ++it) {
    if (it + 1 < NITER) {
      const bf16x8* src = wv + (size_t)(it + 1) * 2048;
#pragma unroll
      for (int i = 0; i < 8; ++i)
        gload_lds16(src + w * 64 + i * 256 + l, &wbuf[cur ^ 1][w * 64 + i * 256]);
    }
    const int nb = it * 32;
#pragma unroll
    for (int nt = 0; nt < 2; ++nt) {
      const __hip_bfloat16* wbase = (const __hip_bfloat16*)&wbuf[cur][0] + nt * 8192 + (size_t)l * 8;
      f32x4 a0 = {0.f, 0.f, 0.f, 0.f}, a1 = a0, a2 = a0, a3 = a0;
#pragma unroll
      for (int j = 0; j < 4; ++j) {
        a0 = __builtin_amdgcn_mfma_f32_16x16x32_bf16(afr[j], *(const bf16x8*)(wbase + j * 512), a0, 0, 0, 0);
        a1 = __builtin_amdgcn_mfma_f32_16x16x32_bf16(afr[4 + j], *(const bf16x8*)(wbase + (4 + j) * 512), a1, 0, 0, 0);
        a2 = __builtin_amdgcn_mfma_f32_16x16x32_bf16(afr[8 + j], *(const bf16x8*)(wbase + (8 + j) * 512), a2, 0, 0, 0);
        a3 = __builtin_amdgcn_mfma_f32_16x16x32_bf16(afr[12 + j], *(const bf16x8*)(wbase + (12 + j) * 512), a3, 0, 0, 0);
      }
      f32x4 acc = (a0 + a1) + (a2 + a3);
      const int n = nb + nt * 16 + m;
      float bias = bias_l[n];
      float mul = mult_l[n];
#pragma unroll
      for (int r = 0; r < 4; ++r) part[r] += fast_tanh(acc[r] + bias) * mul;
    }
    __syncthreads();  // vmcnt(0)+lgkmcnt(0) drain AFTER compute, then barrier
    cur ^= 1;
  }
#pragma unroll
  for (int r = 0; r < 4; ++r) {
    part[r] += __shfl_xor(part[r], 1, 64);
    part[r] += __shfl_xor(part[r], 2, 64);
    part[r] += __shfl_xor(part[r], 4, 64);
    part[r] += __shfl_xor(part[r], 8, 64);
  }
  if (m == 0) {
#pragma unroll
    for (int r = 0; r < 4; ++r) {
      int s = st * 16 + q * 4 + r;
      float v = part[r];
      if (MODE == 1 && enc_idx[b * SS + s] == 0) v -= 1000.0f;
      out[b * SS + s] = v;
    }
  }
}

// ---- score_g via MFMA, barrier-free, fused per-block row max/expsum partials ----
__global__ __launch_bounds__(256, 4) void k_score_g2(
    const __hip_bfloat16* __restrict__ ypk, const float* __restrict__ Wo_w,
    const float* __restrict__ Wo_b, float* __restrict__ sg,
    float* __restrict__ ppmax, float* __restrict__ ppsum) {
  const int t = threadIdx.x;
  const int l = t & 63, w = t >> 6;
  const int m = l & 15, q = l >> 4;
  const int blk = blockIdx.x;
  const int n = blk * 64 + w * 16 + m;
  const int n_ld = (n < VV) ? n : (VV - 1);
  const float* wrow = Wo_w + (size_t)n_ld * 1024;
  f32x4 acc[8];
#pragma unroll
  for (int mt = 0; mt < 8; ++mt) acc[mt] = (f32x4){0.f, 0.f, 0.f, 0.f};

  for (int ks = 0; ks < 32; ++ks) {
    bf16x8 bfr = cvt8(wrow + ks * 32 + q * 8);
#pragma unroll
    for (int mt = 0; mt < 8; ++mt) {
      bf16x8 af = *(const bf16x8*)(ypk + (((size_t)mt * 32 + ks) * 64 + l) * 8);
      acc[mt] = __builtin_amdgcn_mfma_f32_16x16x32_bf16(af, bfr, acc[mt], 0, 0, 0);
    }
  }

  float bv = (n < VV) ? Wo_b[n] : 0.f;
#pragma unroll
  for (int mt = 0; mt < 8; ++mt) {
#pragma unroll
    for (int r = 0; r < 4; ++r) {
      float v = acc[mt][r] + bv;
      if (n < VV)
        sg[(size_t)(mt * 16 + q * 4 + r) * VV + n] = v;
      else
        v = -1e30f;
      acc[mt][r] = v;
    }
  }

  __shared__ float redA[4][128];
  __shared__ float MS[128];
#pragma unroll
  for (int mt = 0; mt < 8; ++mt) {
#pragma unroll
    for (int r = 0; r < 4; ++r) {
      float mx = acc[mt][r];
      mx = fmaxf(mx, __shfl_xor(mx, 1, 64));
      mx = fmaxf(mx, __shfl_xor(mx, 2, 64));
      mx = fmaxf(mx, __shfl_xor(mx, 4, 64));
      mx = fmaxf(mx, __shfl_xor(mx, 8, 64));
      if (m == 0) redA[w][mt * 16 + q * 4 + r] = mx;
    }
  }
  __syncthreads();
  if (t < 128)
    MS[t] = fmaxf(fmaxf(redA[0][t], redA[1][t]), fmaxf(redA[2][t], redA[3][t]));
  __syncthreads();
#pragma unroll
  for (int mt = 0; mt < 8; ++mt) {
#pragma unroll
    for (int r = 0; r < 4; ++r) {
      float s = __expf(acc[mt][r] - MS[mt * 16 + q * 4 + r]);
      s += __shfl_xor(s, 1, 64);
      s += __shfl_xor(s, 2, 64);
      s += __shfl_xor(s, 4, 64);
      s += __shfl_xor(s, 8, 64);
      if (m == 0) redA[w][mt * 16 + q * 4 + r] = s;
    }
  }
  __syncthreads();
  if (t < 128) {
    ppmax[(size_t)t * PST + blk] = MS[t];
    ppsum[(size_t)t * PST + blk] = redA[0][t] + redA[1][t] + redA[2][t] + redA[3][t];
  }
}

// ---- merge partials + sc, and compute prob_c / pc_total (fused old probc math) ----
__global__ void k_merge(const float* __restrict__ ppmax, const float* __restrict__ ppsum,
                        const float* __restrict__ sc,
                        float* __restrict__ rmax, float* __restrict__ rsum,
                        float* __restrict__ prob_c, float* __restrict__ pc_total) {
  const int row = blockIdx.x, t = threadIdx.x;  // 256 threads
  __shared__ float rb[8];
  __shared__ float MS[2];
  float x_sc = sc[row * SS + t];
  float mrow = x_sc;
  for (int i = t; i < NBLK; i += 256) mrow = fmaxf(mrow, ppmax[(size_t)row * PST + i]);
  for (int off = 32; off > 0; off >>= 1) mrow = fmaxf(mrow, __shfl_xor(mrow, off, 64));
  if ((t & 63) == 0) rb[t >> 6] = mrow;
  __syncthreads();
  if (t == 0) MS[0] = fmaxf(fmaxf(rb[0], rb[1]), fmaxf(rb[2], rb[3]));
  __syncthreads();
  float M = MS[0];
  float e_sc = __expf(x_sc - M);
  float s = e_sc;
  for (int i = t; i < NBLK; i += 256)
    s += ppsum[(size_t)row * PST + i] * __expf(ppmax[(size_t)row * PST + i] - M);
  for (int off = 32; off > 0; off >>= 1) s += __shfl_xor(s, off, 64);
  if ((t & 63) == 0) rb[4 + (t >> 6)] = s;
  __syncthreads();
  if (t == 0) MS[1] = rb[4] + rb[5] + rb[6] + rb[7];
  __syncthreads();
  float S = MS[1];
  if (t == 0) {
    rmax[row] = M;
    rsum[row] = S;
  }
  float pc = e_sc / S;
  prob_c[row * SS + t] = pc;
  float ps = pc;
  for (int off = 32; off > 0; off >>= 1) ps += __shfl_xor(ps, off, 64);
  if ((t & 63) == 0) rb[t >> 6] = ps;
  __syncthreads();
  if (t == 0) atomicAdd(pc_total, rb[0] + rb[1] + rb[2] + rb[3]);
}

// ---- fused softmax + context + y assembly + ypk pack ----
__global__ void k_ctx(const float* __restrict__ score, const float* __restrict__ enc,
                      const float* __restrict__ state, float* __restrict__ y,
                      __hip_bfloat16* __restrict__ ypk) {
  const int b = blockIdx.x, hc = blockIdx.y, t = threadIdx.x;  // 128 threads
  __shared__ float aws[SS];
  __shared__ float rb[4];
  float x0 = score[b * SS + t], x1 = score[b * SS + t + 128];
  float mx = fmaxf(x0, x1);
  for (int off = 32; off > 0; off >>= 1) mx = fmaxf(mx, __shfl_xor(mx, off, 64));
  if ((t & 63) == 0) rb[t >> 6] = mx;
  __syncthreads();
  mx = fmaxf(rb[0], rb[1]);
  float e0 = __expf(x0 - mx), e1 = __expf(x1 - mx);
  float s = e0 + e1;
  for (int off = 32; off > 0; off >>= 1) s += __shfl_xor(s, off, 64);
  if ((t & 63) == 0) rb[2 + (t >> 6)] = s;
  __syncthreads();
  float inv = 1.0f / (rb[2] + rb[3]);
  aws[t] = e0 * inv;
  aws[t + 128] = e1 * inv;
  __syncthreads();
  const int h = hc * 128 + t;
  float acc = 0.f;
#pragma unroll 8
  for (int ss = 0; ss < SS; ++ss) acc += aws[ss] * enc[((size_t)b * SS + ss) * HH + h];
  float sv = state[b * HH + h];
  y[(size_t)b * 1024 + h] = sv;
  y[(size_t)b * 1024 + HH + h] = acc;
  // ypk pack: element (row=b, col): idx = ((tile*32 + ks)*64 + q*16 + m)*8 + e
  const int tile = b >> 4, mm = b & 15;
  const int c0 = h, c1 = HH + h;
  ypk[(((size_t)tile * 32 + (c0 >> 5)) * 64 + ((c0 & 31) >> 3) * 16 + mm) * 8 + (c0 & 7)] =
      __float2bfloat16(sv);
  ypk[(((size_t)tile * 32 + (c1 >> 5)) * 64 + ((c1 & 31) >> 3) * 16 + mm) * 8 + (c1 & 7)] =
      __float2bfloat16(acc);
}

__global__ void k_write_probg(const float* __restrict__ sg,
                              const float* __restrict__ rmax,
                              const float* __restrict__ rsum,
                              float* __restrict__ out) {
  int i = blockIdx.x * 256 + threadIdx.x;
  const int total = BB * VEXT;
  if (i >= total) return;
  int b = i / VEXT;
  int v = i - b * VEXT;
  float val;
  if (v < VV)
    val = __expf(sg[(size_t)b * VV + v] - rmax[b]) / rsum[b];
  else
    val = 1e-4f;
  out[i] = val;
}

// ---- weighted_new (h-split) + prob_c scatter into out (hc==0 only; runs after probg) ----
__global__ void k_weighted2(const int* __restrict__ enc_idx,
                            const int* __restrict__ input_idx,
                            const float* __restrict__ prob_c,
                            const float* __restrict__ pc_total,
                            const float* __restrict__ enc,
                            float* __restrict__ wout,
                            float* __restrict__ out) {
  const int b = blockIdx.x, hc = blockIdx.y, t = threadIdx.x;  // 128 threads
  __shared__ float f[SS];
  __shared__ float rb[2];
  const int idx_in = input_idx[b];
  const int e0i = enc_idx[b * SS + t], e1i = enc_idx[b * SS + t + 128];
  const float p0 = prob_c[b * SS + t], p1 = prob_c[b * SS + t + 128];
  if (hc == 0) {
    atomicAdd(&out[(size_t)b * VEXT + e0i], p0);
    atomicAdd(&out[(size_t)b * VEXT + e1i], p1);
  }
  int m0 = (e0i == idx_in) ? 1 : 0;
  int m1 = (e1i == idx_in) ? 1 : 0;
  float lsum = (float)(m0 + m1);
  for (int off = 32; off > 0; off >>= 1) lsum += __shfl_xor(lsum, off, 64);
  if ((t & 63) == 0) rb[t >> 6] = lsum;
  __syncthreads();
  float tot = rb[0] + rb[1];
  float norm = (tot > 1.0f) ? 1.0f / tot : 1.0f;
  float inv_pct = 1.0f / pc_total[0];
  f[t] = m0 ? p0 * inv_pct * norm : 0.f;
  f[t + 128] = m1 ? p1 * inv_pct * norm : 0.f;
  __syncthreads();
  const int h = hc * 128 + t;
  float acc = 0.f;
  for (int ss = 0; ss < SS; ++ss) acc += f[ss] * enc[((size_t)b * SS + ss) * HH + h];
  wout[b * HH + h] = acc;
}

extern "C" void kernel_launch(void* const* d_in, const int* in_sizes, int n_in,
                              void* d_out, int out_size, void* d_ws, size_t ws_size,
                              hipStream_t stream) {
  const int* input_idx = (const int*)d_in[0];
  const float* encoded = (const float*)d_in[1];
  const int* encoded_idx = (const int*)d_in[2];
  const float* prev_state = (const float*)d_in[3];
  const float* embed = (const float*)d_in[5];
  const float* Ws_w = (const float*)d_in[6];
  const float* Ws_b = (const float*)d_in[7];
  const float* gWih = (const float*)d_in[8];
  const float* gWhh = (const float*)d_in[9];
  const float* gbih = (const float*)d_in[10];
  const float* gbhh = (const float*)d_in[11];
  const float* attn_W = (const float*)d_in[12];
  const float* attn_b = (const float*)d_in[13];
  const float* attn_v = (const float*)d_in[14];
  const float* Wo_w = (const float*)d_in[15];
  const float* Wo_b = (const float*)d_in[16];
  const float* Wc_w = (const float*)d_in[17];
  const float* Wc_b = (const float*)d_in[18];

  float* out = (float*)d_out;
  float* out_state = out + (size_t)BB * VEXT;
  float* out_weighted = out_state + BB * HH;

  float* ws = (float*)d_ws;
  float* prevv = ws;                          // 65536
  float* state = prevv + BB * HH;             // 65536
  float* hW = state + BB * HH;                // 65536
  float* ascore = hW + BB * HH;               // 32768
  float* aw = ascore + BB * SS;               // 32768 (unused, kept for layout)
  float* y = aw + BB * SS;                    // 131072
  float* sg = y + BB * 1024;                  // 6400000 (gi/gh alias its head pre-score_g)
  float* sc = sg + (size_t)BB * VV;           // 32768
  float* prob_c = sc + BB * SS;               // 32768
  float* rmax = prob_c + BB * SS;             // 128
  float* rsum = rmax + BB;                    // 128
  float* pc_total = rsum + BB;                // 64 (padded)
  float* ppmax = pc_total + 64;               // 128*784
  float* ppsum = ppmax + (size_t)BB * PST;    // 128*784
  __hip_bfloat16* wc_bf = (__hip_bfloat16*)(ppsum + (size_t)BB * PST);  // 1024*512
  __hip_bfloat16* wa_bf = wc_bf + (size_t)1024 * HH;                    // 512*512
  __hip_bfloat16* epack = wa_bf + (size_t)512 * HH;                     // 128*256*512
  __hip_bfloat16* ypk = epack + (size_t)BB * SS * HH;                   // 128*1024

  float* gi = sg;                 // 128*1536, dead before sg is written
  float* gh = sg + BB * 1536;     // 128*1536

  // pack weights + encoded into MFMA fragment order; zero pc_total
  k_pack_all<<<8576, 256, 0, stream>>>(Wc_w, attn_W, encoded, wc_bf, wa_bf, epack, pc_total);

  // GRU chain: prevv + gi in one dual launch (independent), then gh, gates, hW
  k_gemm_dual<<<32, 256, 0, stream>>>(prev_state, Ws_w, Ws_b, prevv, 512, 512, 8,
                                      embed, gWih, gbih, gi, 1024, 1536, input_idx);
  k_gemm_bt<512, false><<<24, 256, 0, stream>>>(prevv, gWhh, gbhh, gh, 1536, nullptr);
  k_gates<<<256, 256, 0, stream>>>(gi, gh, prevv, state, out_state);
  k_gemm_bt<1024, false><<<8, 256, 0, stream>>>(state, attn_W, attn_b, hW, 512, nullptr);

  k_fused3<HH, 0><<<dim3(BB, 4), 256, 0, stream>>>(epack, wa_bf, hW, attn_v,
                                                   nullptr, ascore);
  k_ctx<<<dim3(BB, 4), 128, 0, stream>>>(ascore, encoded, state, y, ypk);

  k_score_g2<<<NBLK, 256, 0, stream>>>(ypk, Wo_w, Wo_b, sg, ppmax, ppsum);
  k_fused3<1024, 1><<<dim3(BB, 4), 256, 0, stream>>>(epack, wc_bf, Wc_b, y,
                                                     encoded_idx, sc);

  k_merge<<<BB, 256, 0, stream>>>(ppmax, ppsum, sc, rmax, rsum, prob_c, pc_total);
  k_write_probg<<<(BB * VEXT + 255) / 256, 256, 0, stream>>>(sg, rmax, rsum, out);
  k_weighted2<<<dim3(BB, 4), 128, 0, stream>>>(encoded_idx, input_idx, prob_c, pc_total,
                                               encoded, out_weighted, out);
}